// Round 1
// 214.020 us; speedup vs baseline: 1.0362x; 1.0362x over previous
//
#include <hip/hip_runtime.h>
#include <hip/hip_bf16.h>
#include <math.h>

// Problem constants (fixed by setup_inputs)
constexpr int B_ = 32;
constexpr int C_ = 256;
constexpr int N_ = 64;
constexpr int S_ = 64;
constexpr int NPIX = N_ * N_;   // 4096
constexpr int P_ = 2080;        // valid (upper-triangle) proposals per video
constexpr int TPB = 33;         // 64-proposal tiles per video (33*64 = 2112 >= 2080)
constexpr int NQ = TPB * B_;    // 1056 inter-query blocks

#define T_V_INV 10.0f
#define T_Q_INV 10.0f
#define NEG_IOU 0.5f

typedef __attribute__((ext_vector_type(8))) short short8;
typedef __attribute__((ext_vector_type(4))) float f32x4;

static __device__ __forceinline__ unsigned short f2bf(float x) {
  __hip_bfloat16 h = __float2bfloat16(x);
  unsigned short u;
  __builtin_memcpy(&u, &h, sizeof(u));
  return u;
}

// ---------------------------------------------------------------------------
// K1 setup: blocks 0..63 = per-sentence (normalize feats -> sf_t fp32 + bf16
// MFMA A-fragments; top-1 valid pixel from iou). Block 64 = scatter_idx +
// triangle flat-index -> pixel table (tab[t] = r*64+col in row-major triangle
// order, t in [0, 2080)).
// ---------------------------------------------------------------------------
__global__ __launch_bounds__(256) void k_setup(
    const float* __restrict__ sents, const float* __restrict__ iou,
    const int* __restrict__ nt,
    float* __restrict__ sf_t, unsigned short* __restrict__ sf_frag,
    int* __restrict__ scatter, int* __restrict__ top_pix,
    int* __restrict__ tab) {
  int bid = blockIdx.x, tid = threadIdx.x;
  __shared__ float wsum[4];
  __shared__ float bval[256];
  __shared__ int bidx[256];

  if (bid < S_) {
    int s = bid, c = tid;
    float v = sents[s * C_ + c];
    float ss = v * v;
    #pragma unroll
    for (int o = 32; o; o >>= 1) ss += __shfl_xor(ss, o);
    if ((c & 63) == 0) wsum[c >> 6] = ss;
    __syncthreads();
    float tot = wsum[0] + wsum[1] + wsum[2] + wsum[3];
    float rn = 1.0f / fmaxf(sqrtf(tot), 1e-12f);
    float o = v * rn;
    sf_t[c * S_ + s] = o;
    // A-fragment layout: A[m=s][k=c], lane = quad*16 + (s&15), elem j = c&7
    int ks = c >> 5, q = (c >> 3) & 3, j = c & 7;
    int mt = s >> 4, m = s & 15;
    sf_frag[((ks * 4 + mt) * 64 + (q * 16 + m)) * 8 + j] = f2bf(o);

    // top-1 valid pixel (ties -> lowest flat index)
    float bv = -1.0f;
    int bi = 0x7fffffff;
    for (int pix = tid; pix < NPIX; pix += 256) {
      int r = pix >> 6, c0 = pix & 63;
      if (c0 >= r) {
        float x = iou[s * NPIX + pix];
        if (x > bv) { bv = x; bi = pix; }
      }
    }
    bval[tid] = bv; bidx[tid] = bi;
    __syncthreads();
    for (int st = 128; st; st >>= 1) {
      if (tid < st) {
        float ov = bval[tid + st]; int oi = bidx[tid + st];
        if (ov > bval[tid] || (ov == bval[tid] && oi < bidx[tid])) {
          bval[tid] = ov; bidx[tid] = oi;
        }
      }
      __syncthreads();
    }
    if (tid == 0) top_pix[s] = bidx[0];
  } else {
    if (tid < S_) {
      int cum = 0, res = 0;
      for (int b = 0; b < B_; b++) {
        int nb = nt[b];
        if (tid >= cum && tid < cum + nb) res = b;
        cum += nb;
      }
      scatter[tid] = res;
    }
    // triangle flat-index -> pixel table
    for (int pix = tid; pix < NPIX; pix += 256) {
      int r = pix >> 6, c0 = pix & 63;
      if (c0 >= r) {
        int t = r * 64 - (r * (r - 1)) / 2 + (c0 - r);
        tab[t] = pix;
      }
    }
  }
}

// ---------------------------------------------------------------------------
// K2 main: blocks [0,NQ) = triangle-packed inter-query MFMA GEMM. Each block
// handles 64 consecutive valid proposals of one video (no dead triangle
// lanes). V loads fully preloaded into 64 regs/thread (one vmcnt burst);
// A-fragments staged once per block into LDS. Blocks [NQ, NQ+64) = the
// inter-video loss (one block per sentence, unchanged).
// ---------------------------------------------------------------------------
__global__ __launch_bounds__(256) void k_main(
    const float* __restrict__ V, const float* __restrict__ iou,
    const short8* __restrict__ Afrag, const float* __restrict__ sf_t,
    const int* __restrict__ scatter, const int* __restrict__ top_pix,
    const int* __restrict__ tab,
    float* __restrict__ partials, float* __restrict__ pos_score,
    float* __restrict__ loss_vid) {
  __shared__ int ssc[S_];
  __shared__ float part[4][S_];
  __shared__ short8 afr[32 * 64];   // 32 KB staged A-fragments
  __shared__ float vh[C_];
  __shared__ float red[4];
  __shared__ float pdm[4][S_];

  int tid = threadIdx.x;

  if (blockIdx.x < NQ) {
    // ============ inter-query path ============
    if (tid < S_) ssc[tid] = scatter[tid];
    for (int i = tid; i < 32 * 64; i += 256) afr[i] = Afrag[i];
    __syncthreads();

    int v = blockIdx.x / TPB, blk = blockIdx.x % TPB;
    int w = tid >> 6, lane = tid & 63;
    int n = lane & 15, q = lane >> 4;
    int t = blk * 64 + w * 16 + n;
    bool valid = (t < P_);
    int tt = valid ? t : (P_ - 1);
    int pix = tab[tt];

    const float* vb = V + (size_t)v * C_ * NPIX + pix;
    const float* vbq = vb + (size_t)(q * 8) * NPIX;

    // Preload all 64 V values (c = ks*32 + q*8 + j) — single load burst.
    float vv[64];
    #pragma unroll
    for (int ks = 0; ks < 8; ks++) {
      #pragma unroll
      for (int j = 0; j < 8; j++) {
        vv[ks * 8 + j] = vbq[(size_t)(ks * 32 + j) * NPIX];
      }
    }

    f32x4 acc[4] = {f32x4{0,0,0,0}, f32x4{0,0,0,0}, f32x4{0,0,0,0}, f32x4{0,0,0,0}};
    float ssq = 0.0f;

    #pragma unroll
    for (int ks = 0; ks < 8; ks++) {
      short8 bfrag;
      #pragma unroll
      for (int j = 0; j < 8; j++) {
        float x = vv[ks * 8 + j];
        ssq = fmaf(x, x, ssq);
        bfrag[j] = (short)f2bf(x);
      }
      #pragma unroll
      for (int mt = 0; mt < 4; mt++) {
        short8 a = afr[(ks * 4 + mt) * 64 + lane];
        acc[mt] = __builtin_amdgcn_mfma_f32_16x16x32_bf16(a, bfrag, acc[mt], 0, 0, 0);
      }
    }

    ssq += __shfl_xor(ssq, 16);
    ssq += __shfl_xor(ssq, 32);
    float rs = T_Q_INV / fmaxf(sqrtf(ssq), 1e-12f);

    // Epilogue: D layout col(pixel)=lane&15, sentence s = mt*16 + q*4 + rr
    #pragma unroll
    for (int mt = 0; mt < 4; mt++) {
      #pragma unroll
      for (int rr = 0; rr < 4; rr++) {
        int s = mt * 16 + q * 4 + rr;
        float e = valid ? __expf(acc[mt][rr] * rs) : 0.0f;
        if (valid && ssc[s] == v) {
          if (iou[s * NPIX + pix] > NEG_IOU) e = 0.0f; // positive -> excluded
        }
        e += __shfl_xor(e, 1);
        e += __shfl_xor(e, 2);
        e += __shfl_xor(e, 4);
        e += __shfl_xor(e, 8); // summed over this wave's 16 proposals
        if (n == 0) part[w][s] = e;
      }
    }
    __syncthreads();
    if (tid < S_) {
      partials[(size_t)blockIdx.x * S_ + tid] =
          part[0][tid] + part[1][tid] + part[2][tid] + part[3][tid];
    }
  } else {
    // ============ inter-video path (one block per sentence) ============
    int s = blockIdx.x - NQ;
    int b = scatter[s];
    int pix = top_pix[s];
    float v = V[((size_t)b * C_ + tid) * NPIX + pix];
    float ss = v * v;
    #pragma unroll
    for (int o = 32; o; o >>= 1) ss += __shfl_xor(ss, o);
    if ((tid & 63) == 0) red[tid >> 6] = ss;
    __syncthreads();
    float tot = red[0] + red[1] + red[2] + red[3];
    float rn = 1.0f / fmaxf(sqrtf(tot), 1e-12f);
    vh[tid] = v * rn;
    __syncthreads();
    int so = tid & 63, chunk = tid >> 6;
    float pd = 0.0f;
    #pragma unroll 8
    for (int c = chunk * 64; c < chunk * 64 + 64; c++)
      pd = fmaf(vh[c], sf_t[c * S_ + so], pd);
    pdm[chunk][so] = pd;
    __syncthreads();
    if (tid < S_) {
      float dot = pdm[0][tid] + pdm[1][tid] + pdm[2][tid] + pdm[3][tid];
      if (tid == s) pos_score[s] = dot;
      float pos = __shfl(dot, s);
      float e = (tid == s) ? 0.0f : __expf(dot * T_V_INV);
      #pragma unroll
      for (int o = 32; o; o >>= 1) e += __shfl_xor(e, o);
      if (tid == 0) {
        float pp = pos * T_V_INV;
        loss_vid[s] = -(pp - logf(__expf(pp) + e));
      }
    }
  }
}

// ---------------------------------------------------------------------------
// K3 final (merged reduce + loss): 1 block x 1024 threads. Phase 1: float4-
// vectorized fold of partials[NQ][64] -> neg[s] (64 rowgroups x 16 col4groups,
// all loads coalesced). Phase 2: both losses, write the two means.
// ---------------------------------------------------------------------------
__global__ __launch_bounds__(1024) void k_fin(
    const float* __restrict__ partials, const float* __restrict__ pos_score,
    const float* __restrict__ loss_vid, float* __restrict__ out) {
  int tid = threadIdx.x;
  __shared__ f32x4 m[64][16];
  const f32x4* p4 = (const f32x4*)partials;
  int s4 = tid & 15, g = tid >> 4; // g in [0,64)
  f32x4 a = {0.0f, 0.0f, 0.0f, 0.0f};
  #pragma unroll 4
  for (int i = g; i < NQ; i += 64) a += p4[i * 16 + s4];
  m[g][s4] = a;
  __syncthreads();
  if (tid < S_) {
    int q4 = tid >> 2, e4 = tid & 3;
    float neg = 0.0f;
    #pragma unroll
    for (int g2 = 0; g2 < 64; g2++) neg += m[g2][q4][e4];
    float p = pos_score[tid] * T_Q_INV;
    float lq = -(p - logf(__expf(p) + neg));
    float lv = loss_vid[tid];
    #pragma unroll
    for (int o = 32; o; o >>= 1) {
      lq += __shfl_xor(lq, o);
      lv += __shfl_xor(lv, o);
    }
    if (tid == 0) {
      out[0] = lv / (float)S_;
      out[1] = lq / (float)S_;
    }
  }
}

// ---------------------------------------------------------------------------
extern "C" void kernel_launch(void* const* d_in, const int* in_sizes, int n_in,
                              void* d_out, int out_size, void* d_ws, size_t ws_size,
                              hipStream_t stream) {
  const float* V     = (const float*)d_in[0]; // [B,C,N,N]
  const float* sents = (const float*)d_in[1]; // [S,C]
  const int*   nt    = (const int*)d_in[2];   // [B]
  const float* iou   = (const float*)d_in[3]; // [S,N,N]
  // d_in[4] = mask2d: structural triu — resolved statically (as in reference)

  float* ws = (float*)d_ws;
  float*          sf_t    = ws;                            // 16384 floats
  unsigned short* sf_frag = (unsigned short*)(ws + 16384); // 16384 bf16 (8192 f)
  int*   scatter   = (int*)(ws + 16384 + 8192);            // 64
  int*   top_pix   = scatter + S_;                         // 64
  float* pos_score = (float*)(top_pix + S_);               // 64
  float* loss_vid  = pos_score + S_;                       // 64
  int*   tab       = (int*)(loss_vid + S_);                // 2112 (pads to 16B)
  float* partials  = (float*)(tab + TPB * 64);             // NQ*64 floats, 16B-aligned

  k_setup<<<S_ + 1, 256, 0, stream>>>(sents, iou, nt, sf_t, sf_frag, scatter,
                                      top_pix, tab);
  k_main <<<NQ + S_, 256, 0, stream>>>(V, iou, (const short8*)sf_frag, sf_t,
                                       scatter, top_pix, tab, partials,
                                       pos_score, loss_vid);
  k_fin  <<<1, 1024, 0, stream>>>(partials, pos_score, loss_vid, (float*)d_out);
}